// Round 16
// baseline (93.665 us; speedup 1.0000x reference)
//
#include <hip/hip_runtime.h>

#define NN 2048
#define DD 64
#define BB 64
#define PP 16384
#define TT 262144
#define EPSF 1e-6f
#define SS ((size_t)NN * DD)  // floats between consecutive bins of v (bin-major)

// ---------------- ws layout (bytes) ----------------
// 0        : double acc
// 1024     : int done
// 17408    : int perm[PP]      (pair ids sorted by node i)
// 82944    : float bounds[65]
// 83456    : float widths[64]
// 83968    : float innerPad[64]
// 84480    : float4 table[PP*BB]  (n2_left, d0, qq, bsum) = 16.78 MB
// 16861696 : ushort vh[NN*BB*DD]  (bf16 node-major v)      = 16.78 MB

typedef unsigned uv2 __attribute__((ext_vector_type(2)));
typedef float fx4 __attribute__((ext_vector_type(4)));
typedef unsigned ux4 __attribute__((ext_vector_type(4)));
using bf16x8 = __attribute__((ext_vector_type(8))) short;
using f32x4v = __attribute__((ext_vector_type(4))) float;

template <int CTRL, int RM = 0xF, bool BC = true>
__device__ __forceinline__ float dpp_add(float x) {
    int y = __builtin_amdgcn_update_dpp(0, __float_as_int(x), CTRL, RM, 0xF, BC);
    return x + __int_as_float(y);
}

template <int PAT>
__device__ __forceinline__ float swz_add(float x) {
    return x + __int_as_float(__builtin_amdgcn_ds_swizzle(__float_as_int(x), PAT));
}

__device__ __forceinline__ float xor16_add(float x) {
#if __has_builtin(__builtin_amdgcn_permlane16_swap)
    uv2 r = __builtin_amdgcn_permlane16_swap(__float_as_uint(x), __float_as_uint(x),
                                             false, false);
    return __uint_as_float(r.x) + __uint_as_float(r.y);
#else
    return swz_add<0x401F>(x);
#endif
}
__device__ __forceinline__ float xor32_add(float x) {
#if __has_builtin(__builtin_amdgcn_permlane32_swap)
    uv2 r = __builtin_amdgcn_permlane32_swap(__float_as_uint(x), __float_as_uint(x),
                                             false, false);
    return __uint_as_float(r.x) + __uint_as_float(r.y);
#else
    return x + __shfl_xor(x, 32, 64);
#endif
}

__device__ __forceinline__ float reduce1(float a) {
    a = dpp_add<0xB1>(a);
    a = dpp_add<0x4E>(a);
    a = dpp_add<0x141>(a);
    a = swz_add<0x201F>(a);
    a = xor16_add(a);
    a = xor32_add(a);
    return a;
}

__device__ __forceinline__ float incl_scan(float x) {
    x = dpp_add<0x111>(x);
    x = dpp_add<0x112>(x);
    x = dpp_add<0x114>(x);
    x = dpp_add<0x118>(x);
    x = dpp_add<0x142, 0xA, false>(x);
    x = dpp_add<0x143, 0xC, false>(x);
    return x;
}

__device__ __forceinline__ unsigned f2bf(float f) {  // RNE, returns low 16 bits
    unsigned u = __float_as_uint(f);
    return (u + 0x7FFFu + ((u >> 16) & 1u)) >> 16;
}
__device__ __forceinline__ float bf_lo(unsigned u) { return __uint_as_float(u << 16); }
__device__ __forceinline__ float bf_hi(unsigned u) { return __uint_as_float(u & 0xFFFF0000u); }

__device__ __forceinline__ unsigned cvt_pk_bf(float lo, float hi) {
    unsigned r;
    asm("v_cvt_pk_bf16_f32 %0, %1, %2" : "=v"(r) : "v"(lo), "v"(hi));
    return r;
}
__device__ __forceinline__ float bpermf(float v, int srclane) {
    return __int_as_float(__builtin_amdgcn_ds_bpermute(srclane << 2, __float_as_int(v)));
}

// Fused pre-pass, one dispatch:
//   blocks [0,1024)  : v[b][n][d] fp32 -> vh[n][b][d] bf16 (contiguous nt reads, full-line writes)
//   block  1024      : bounds/widths/innerPad + zero acc/done
//   block  1025      : full pair sort by node i (hist+scan+scatter in LDS)
__global__ __launch_bounds__(1024) void k_pre(
    const float* __restrict__ v, unsigned* __restrict__ vh32,
    const float* __restrict__ brw, float* __restrict__ bounds,
    float* __restrict__ widths, float* __restrict__ innerPad,
    const int* __restrict__ pairs, int* __restrict__ perm,
    double* __restrict__ acc, int* __restrict__ done) {
    __shared__ int scnt[2048];
    __shared__ int waveTot[16];
    __shared__ int waveOff[16];
    const int bid = blockIdx.x;
    const int tid = threadIdx.x;

    if (bid < 1024) {  // ---- convert: block covers bin (bid>>4), nodes [(bid&15)*128, +128)
        const int bin = bid >> 4;
        const int node0 = (bid & 15) << 7;
        const fx4* __restrict__ src =
            (const fx4*)(v + (size_t)bin * SS + (size_t)node0 * DD);
        fx4 f0 = __builtin_nontemporal_load(src + tid * 2);
        fx4 f1 = __builtin_nontemporal_load(src + tid * 2 + 1);
        const int nn = tid >> 3;         // node within chunk
        const int d = (tid & 7) * 8;     // dim start
        ux4 o;
        o.x = f2bf(f0.x) | (f2bf(f0.y) << 16);
        o.y = f2bf(f0.z) | (f2bf(f0.w) << 16);
        o.z = f2bf(f1.x) | (f2bf(f1.y) << 16);
        o.w = f2bf(f1.z) | (f2bf(f1.w) << 16);
        *(ux4*)(vh32 + (size_t)(node0 + nn) * 2048 + bin * 32 + d / 2) = o;
        return;
    }

    if (bid == 1024) {  // ---- bounds + zero
        if (tid == 64) *acc = 0.0;
        if (tid == 65) *done = 0;
        if (tid >= 64) return;
        int lane = tid;
        float w = brw[lane];
        float m = w;
#pragma unroll
        for (int s = 32; s >= 1; s >>= 1) m = fmaxf(m, __shfl_xor(m, s, 64));
        float e = expf(w - m);
        float tot = e;
#pragma unroll
        for (int s = 32; s >= 1; s >>= 1) tot += __shfl_xor(tot, s, 64);
        float sm = e / tot;
        float c = sm;
#pragma unroll
        for (int off = 1; off < 64; off <<= 1) {
            float t = __shfl_up(c, off, 64);
            if (lane >= off) c += t;
        }
        float cexcl = __shfl_up(c, 1, 64);
        if (lane == 0) cexcl = 0.f;
        if (lane == 0) bounds[0] = 0.f;
        bounds[lane + 1] = c;
        widths[lane] = c - cexcl;
        innerPad[lane] = (lane == 63) ? 3.4e38f : c;
        return;
    }

    // ---- bid == 1025: single-block sort of pairs by node i
    scnt[tid] = 0;
    scnt[tid + 1024] = 0;
    __syncthreads();
#pragma unroll
    for (int k = 0; k < 16; k++) atomicAdd(&scnt[pairs[k * 1024 + tid]], 1);
    __syncthreads();
    int a = scnt[tid * 2], b2 = scnt[tid * 2 + 1];
    int s = a + b2;
    int lane = tid & 63, wid = tid >> 6;
    int incl = s;
#pragma unroll
    for (int off = 1; off < 64; off <<= 1) {
        int t2 = __shfl_up(incl, off, 64);
        if (lane >= off) incl += t2;
    }
    if (lane == 63) waveTot[wid] = incl;
    __syncthreads();
    if (tid == 0) {
        int r = 0;
        for (int w = 0; w < 16; w++) { waveOff[w] = r; r += waveTot[w]; }
    }
    __syncthreads();
    int run = waveOff[wid] + (incl - s);
    scnt[tid * 2] = run;           // cursors (own slots only -> no hazard)
    scnt[tid * 2 + 1] = run + a;
    __syncthreads();
#pragma unroll
    for (int k = 0; k < 16; k++) {
        int idx = k * 1024 + tid;
        int pos = atomicAdd(&scnt[pairs[idx]], 1);
        perm[pos] = idx;
    }
}

// 8 pairs per wave, 2-deep double-buffered staging (round-14 structure) +
// nontemporal table stores (keep vh L2-resident) + setprio around MFMA.
__global__ __launch_bounds__(256, 2) void k_pairs(
    const float* __restrict__ x0, const uint4* __restrict__ vh4,
    const float* __restrict__ beta, const int* __restrict__ pairs,
    const int* __restrict__ perm, const float* __restrict__ widths,
    float* __restrict__ table, double* __restrict__ acc_out) {
    __shared__ double bacc[4];
    const int wid = threadIdx.x >> 6;
    const int lane = threadIdx.x & 63;
    const int bid = blockIdx.x;
    const int vb = ((bid & 7) << 6) | (bid >> 3);  // XCD swizzle over 512 blocks
    const int pbase = (vb * 4 + wid) * 8;

    int pk[8], ik[8], jk[8];
    float bs[8];
#pragma unroll
    for (int k = 0; k < 8; k++) pk[k] = perm[pbase + k];
#pragma unroll
    for (int k = 0; k < 8; k++) {
        ik[k] = pairs[pk[k]];
        jk[k] = pairs[PP + pk[k]];
    }
#pragma unroll
    for (int k = 0; k < 8; k++) bs[k] = beta[ik[k]] + beta[jk[k]];

    float wv[4][4];
#pragma unroll
    for (int tm = 0; tm < 4; tm++)
#pragma unroll
        for (int r = 0; r < 4; r++)
            wv[tm][r] = widths[16 * tm + (lane >> 4) * 4 + r];
    const float wl = widths[lane];
    const int laneterm = (lane & 15) * 8 + (lane >> 4);
    const int nl = lane & 15;
    const int mb = (lane >> 4) * 4;

    uint4 ra0[8], rb0[8], ra1[8], rb1[8];
    float xi0, xj0, xi1, xj1;

#define ISSUE(RA, RB, XI, XJ, k_)                                            \
    {                                                                        \
        const uint4* Vi = vh4 + (size_t)ik[k_] * 512 + laneterm;             \
        const uint4* Vj = vh4 + (size_t)jk[k_] * 512 + laneterm;             \
        _Pragma("unroll") for (int t = 0; t < 4; t++) {                      \
            RA[t * 2 + 0] = Vi[t * 128];                                     \
            RA[t * 2 + 1] = Vi[t * 128 + 4];                                 \
            RB[t * 2 + 0] = Vj[t * 128];                                     \
            RB[t * 2 + 1] = Vj[t * 128 + 4];                                 \
        }                                                                    \
        XI = x0[ik[k_] * DD + lane];                                         \
        XJ = x0[jk[k_] * DD + lane];                                         \
    }

    double accd = 0.0;

#define STEP(RA, RB, XI, XJ, k_, NEXTISSUE)                                                    \
    {                                                                                          \
        const float bsum = bs[k_];                                                             \
        float dx0 = XI - XJ;                                                                   \
        float n2_0 = reduce1(dx0 * dx0);                                                       \
        float rr0 = __builtin_amdgcn_sqrtf(n2_0);                                              \
        float numer0 = rr0 * __expf(bsum - rr0);                                               \
        bf16x8 F[8];                                                                           \
        _Pragma("unroll") for (int f = 0; f < 8; f++) {                                        \
            uint4 q;                                                                           \
            q.x = cvt_pk_bf(bf_lo(RA[f].x) - bf_lo(RB[f].x), bf_hi(RA[f].x) - bf_hi(RB[f].x)); \
            q.y = cvt_pk_bf(bf_lo(RA[f].y) - bf_lo(RB[f].y), bf_hi(RA[f].y) - bf_hi(RB[f].y)); \
            q.z = cvt_pk_bf(bf_lo(RA[f].z) - bf_lo(RB[f].z), bf_hi(RA[f].z) - bf_hi(RB[f].z)); \
            q.w = cvt_pk_bf(bf_lo(RA[f].w) - bf_lo(RB[f].w), bf_hi(RA[f].w) - bf_hi(RB[f].w)); \
            union { uint4 u; bf16x8 s; } cv;                                                   \
            cv.u = q;                                                                          \
            F[f] = cv.s;                                                                       \
        }                                                                                      \
        NEXTISSUE                                                                              \
        bf16x8 AX[2];                                                                          \
        _Pragma("unroll") for (int kb = 0; kb < 2; kb++) {                                     \
            unsigned u[4];                                                                     \
            _Pragma("unroll") for (int c2 = 0; c2 < 4; c2++) {                                 \
                int k0 = kb * 32 + ((lane >> 4) << 3) + c2 * 2;                                \
                u[c2] = cvt_pk_bf(bpermf(dx0, k0), bpermf(dx0, k0 + 1));                       \
            }                                                                                  \
            uint4 q;                                                                           \
            bool z = (lane & 15) != 0;                                                         \
            q.x = z ? 0u : u[0]; q.y = z ? 0u : u[1];                                          \
            q.z = z ? 0u : u[2]; q.w = z ? 0u : u[3];                                          \
            union { uint4 uu; bf16x8 s; } cv;                                                  \
            cv.uu = q;                                                                         \
            AX[kb] = cv.s;                                                                     \
        }                                                                                      \
        __builtin_amdgcn_s_setprio(1);                                                         \
        f32x4v g00 = {0.f, 0.f, 0.f, 0.f}, g01 = g00, g02 = g00, g03 = g00;                    \
        f32x4v g11 = g00, g12 = g00, g13 = g00, g22 = g00, g23 = g00, g33 = g00;               \
        GMM(g00, 0, 0) GMM(g01, 0, 1) GMM(g02, 0, 2) GMM(g03, 0, 3)                            \
        GMM(g11, 1, 1) GMM(g12, 1, 2) GMM(g13, 1, 3)                                           \
        GMM(g22, 2, 2) GMM(g23, 2, 3) GMM(g33, 3, 3)                                           \
        float c00, c01, c02, c03;                                                              \
        {                                                                                      \
            f32x4v ca = {0.f, 0.f, 0.f, 0.f};                                                  \
            CMM(0) c00 = ca[0]; ca = {0.f, 0.f, 0.f, 0.f};                                     \
            CMM(1) c01 = ca[0]; ca = {0.f, 0.f, 0.f, 0.f};                                     \
            CMM(2) c02 = ca[0]; ca = {0.f, 0.f, 0.f, 0.f};                                     \
            CMM(3) c03 = ca[0];                                                                \
        }                                                                                      \
        __builtin_amdgcn_s_setprio(0);                                                         \
        float c0v;                                                                             \
        {                                                                                      \
            float b0 = bpermf(c00, lane & 15);                                                 \
            float b1 = bpermf(c01, lane & 15);                                                 \
            float b2 = bpermf(c02, lane & 15);                                                 \
            float b3 = bpermf(c03, lane & 15);                                                 \
            int g = lane >> 4;                                                                 \
            c0v = (g == 0) ? b0 : (g == 1) ? b1 : (g == 2) ? b2 : b3;                          \
        }                                                                                      \
        float Sv = 0.f, qv = 0.f;                                                              \
        { float sp = 0.f, qp = 0.f;                                 DIAG(g00, 0) FINTN(0) }    \
        { float sp = OFFT(g01, 0), qp = 0.f;                        DIAG(g11, 1) FINTN(1) }    \
        { float sp = OFFT(g02, 0) + OFFT(g12, 1), qp = 0.f;         DIAG(g22, 2) FINTN(2) }    \
        { float sp = OFFT(g03, 0) + OFFT(g13, 1) + OFFT(g23, 2), qp = 0.f;                     \
                                                                    DIAG(g33, 3) FINTN(3) }    \
        float d0r = c0v + Sv;                                                                  \
        float qqr = qv;                                                                        \
        float tt = wl * fmaf(wl, qqr, 2.f * d0r);                                              \
        float incl = incl_scan(tt);                                                            \
        float n2L = fmaxf(n2_0 + (incl - tt), 0.f);                                            \
        float n2R = fmaxf(n2_0 + incl, 0.f);                                                   \
        float rrR = __builtin_amdgcn_sqrtf(n2R);                                               \
        float numerR = rrR * __expf(bsum - rrR);                                               \
        float numerL = __int_as_float(                                                         \
            __builtin_amdgcn_update_dpp(0, __float_as_int(numerR), 0x138, 0xF, 0xF, true));    \
        numerL = (lane == 0) ? numer0 : numerL;                                                \
        float pd = fmaf(wl, qqr, d0r);                                                         \
        float term = numerR * __builtin_amdgcn_rcpf(pd + EPSF)                                 \
                   - numerL * __builtin_amdgcn_rcpf(d0r + EPSF);                               \
        float acc = reduce1(term);                                                             \
        fx4 outv;                                                                              \
        outv.x = n2L; outv.y = d0r; outv.z = qqr; outv.w = bsum;                               \
        __builtin_nontemporal_store(outv,                                                      \
            (fx4*)(table + ((size_t)pk[k_] * BB + lane) * 4));                                 \
        accd += (double)acc;                                                                   \
    }

#define GMM(acc, ta, tb)                                                                       \
    acc = __builtin_amdgcn_mfma_f32_16x16x32_bf16(F[(ta)*2 + 0], F[(tb)*2 + 0], acc, 0, 0, 0); \
    acc = __builtin_amdgcn_mfma_f32_16x16x32_bf16(F[(ta)*2 + 1], F[(tb)*2 + 1], acc, 0, 0, 0);
#define CMM(tb)                                                                       \
    ca = __builtin_amdgcn_mfma_f32_16x16x32_bf16(AX[0], F[(tb)*2 + 0], ca, 0, 0, 0); \
    ca = __builtin_amdgcn_mfma_f32_16x16x32_bf16(AX[1], F[(tb)*2 + 1], ca, 0, 0, 0);
#define OFFT(gt, t_) (wv[t_][0] * gt[0] + wv[t_][1] * gt[1] + wv[t_][2] * gt[2] + wv[t_][3] * gt[3])
#define DIAG(d, t_)                                       \
    sp += (mb + 0 < nl) ? wv[t_][0] * d[0] : 0.f;         \
    sp += (mb + 1 < nl) ? wv[t_][1] * d[1] : 0.f;         \
    sp += (mb + 2 < nl) ? wv[t_][2] * d[2] : 0.f;         \
    sp += (mb + 3 < nl) ? wv[t_][3] * d[3] : 0.f;         \
    qp += (mb + 0 == nl) ? d[0] : 0.f;                    \
    qp += (mb + 1 == nl) ? d[1] : 0.f;                    \
    qp += (mb + 2 == nl) ? d[2] : 0.f;                    \
    qp += (mb + 3 == nl) ? d[3] : 0.f;
#define FINTN(t_)                                         \
    sp = xor16_add(sp); sp = xor32_add(sp);               \
    qp = xor16_add(qp); qp = xor32_add(qp);               \
    if ((lane >> 4) == t_) { Sv = sp; qv = qp; }

    ISSUE(ra0, rb0, xi0, xj0, 0)
    ISSUE(ra1, rb1, xi1, xj1, 1)

    STEP(ra0, rb0, xi0, xj0, 0, ISSUE(ra0, rb0, xi0, xj0, 2))
    STEP(ra1, rb1, xi1, xj1, 1, ISSUE(ra1, rb1, xi1, xj1, 3))
    STEP(ra0, rb0, xi0, xj0, 2, ISSUE(ra0, rb0, xi0, xj0, 4))
    STEP(ra1, rb1, xi1, xj1, 3, ISSUE(ra1, rb1, xi1, xj1, 5))
    STEP(ra0, rb0, xi0, xj0, 4, ISSUE(ra0, rb0, xi0, xj0, 6))
    STEP(ra1, rb1, xi1, xj1, 5, ISSUE(ra1, rb1, xi1, xj1, 7))
    STEP(ra0, rb0, xi0, xj0, 6, )
    STEP(ra1, rb1, xi1, xj1, 7, )

#undef ISSUE
#undef STEP
#undef GMM
#undef CMM
#undef OFFT
#undef DIAG
#undef FINTN

    if (lane == 0) bacc[wid] = accd;
    __syncthreads();
    if (threadIdx.x == 0)
        atomicAdd(acc_out, bacc[0] + bacc[1] + bacc[2] + bacc[3]);
}

// events + fused finalize (last block writes the output)
__global__ __launch_bounds__(256) void k_events(
    const float* __restrict__ times, const int* __restrict__ epid,
    const float* __restrict__ bounds, const float* __restrict__ innerPad,
    const float4* __restrict__ table, double* __restrict__ acc_out,
    int* __restrict__ done, float* __restrict__ out) {
    __shared__ float si[64];
    __shared__ float sb[BB + 1];
    __shared__ double wacc[4];
    int tid = threadIdx.x;
    if (tid < 64) si[tid] = innerPad[tid];
    if (tid <= BB) sb[tid] = bounds[tid];
    __syncthreads();
    int g = (blockIdx.x * 256 + tid) * 2;
    float2 tm2 = *(const float2*)(times + g);
    int2 pd2 = *(const int2*)(epid + g);
    float tms[2] = {tm2.x, tm2.y};
    int pids[2] = {pd2.x, pd2.y};
    int cc[2];
    float rem[2];
#pragma unroll
    for (int k = 0; k < 2; k++) {
        int c = 0;
        float tm = tms[k];
#pragma unroll
        for (int s = 32; s >= 1; s >>= 1)
            if (si[c + s - 1] <= tm) c += s;
        cc[k] = c;
        rem[k] = tm - sb[c];
    }
    float4 e0 = table[(size_t)pids[0] * BB + cc[0]];
    float4 e1 = table[(size_t)pids[1] * BB + cc[1]];
    float eacc;
    {
        float d2 = fmaxf(fmaf(rem[0], fmaf(rem[0], e0.z, 2.f * e0.y), e0.x), 0.f);
        eacc = e0.w - __builtin_amdgcn_sqrtf(d2);
        d2 = fmaxf(fmaf(rem[1], fmaf(rem[1], e1.z, 2.f * e1.y), e1.x), 0.f);
        eacc += e1.w - __builtin_amdgcn_sqrtf(d2);
    }
    float val = reduce1(eacc);
    if ((tid & 63) == 0) wacc[tid >> 6] = (double)val;
    __syncthreads();
    if (tid == 0) {
        atomicAdd(acc_out, -(wacc[0] + wacc[1] + wacc[2] + wacc[3]));
        __threadfence();
        int c = atomicAdd(done, 1);
        if (c == (int)gridDim.x - 1) {
            double a = atomicAdd(acc_out, 0.0);  // atomic read: all adds visible
            out[0] = (float)a;
        }
    }
}

extern "C" void kernel_launch(void* const* d_in, const int* in_sizes, int n_in,
                              void* d_out, int out_size, void* d_ws, size_t ws_size,
                              hipStream_t stream) {
    const float* x0     = (const float*)d_in[0];
    const float* v      = (const float*)d_in[1];
    const float* beta   = (const float*)d_in[2];
    const float* brw    = (const float*)d_in[3];
    const float* etimes = (const float*)d_in[4];
    const int*   pairs  = (const int*)d_in[5];
    const int*   epid   = (const int*)d_in[6];

    char* ws = (char*)d_ws;
    double* acc     = (double*)ws;
    int* done       = (int*)(ws + 1024);
    int* perm       = (int*)(ws + 17408);
    float* bounds   = (float*)(ws + 82944);
    float* widths   = (float*)(ws + 83456);
    float* innerPad = (float*)(ws + 83968);
    float* table    = (float*)(ws + 84480);
    unsigned* vh32  = (unsigned*)(ws + 84480 + (size_t)PP * BB * 16);

    hipLaunchKernelGGL(k_pre, dim3(1026), dim3(1024), 0, stream, v, vh32, brw,
                       bounds, widths, innerPad, pairs, perm, acc, done);
    hipLaunchKernelGGL(k_pairs, dim3(PP / 32), dim3(256), 0, stream, x0, (const uint4*)vh32,
                       beta, pairs, perm, widths, table, acc);
    hipLaunchKernelGGL(k_events, dim3(TT / 512), dim3(256), 0, stream, etimes, epid,
                       bounds, innerPad, (const float4*)table, acc, done, (float*)d_out);
}

// Round 17
// 91.247 us; speedup vs baseline: 1.0265x; 1.0265x over previous
//
#include <hip/hip_runtime.h>

#define NN 2048
#define DD 64
#define BB 64
#define PP 16384
#define TT 262144
#define EPSF 1e-6f
#define SS ((size_t)NN * DD)  // floats between consecutive bins of v (bin-major)

// ---------------- ws layout (bytes) ----------------
// 0        : double acc
// 1024     : int done
// 17408    : int perm[PP]      (pair ids sorted by node i)
// 82944    : float bounds[65]
// 83456    : float widths[64]
// 83968    : float innerPad[64]
// 84480    : float4 table[PP*BB]  (n2_left, d0, qq, bsum) = 16.78 MB
// 16861696 : ushort vh[NN*BB*DD]  (bf16 node-major v)      = 16.78 MB

typedef unsigned uv2 __attribute__((ext_vector_type(2)));
typedef float fx4 __attribute__((ext_vector_type(4)));
typedef unsigned ux4 __attribute__((ext_vector_type(4)));
using bf16x8 = __attribute__((ext_vector_type(8))) short;
using f32x4v = __attribute__((ext_vector_type(4))) float;

template <int CTRL, int RM = 0xF, bool BC = true>
__device__ __forceinline__ float dpp_add(float x) {
    int y = __builtin_amdgcn_update_dpp(0, __float_as_int(x), CTRL, RM, 0xF, BC);
    return x + __int_as_float(y);
}

template <int PAT>
__device__ __forceinline__ float swz_add(float x) {
    return x + __int_as_float(__builtin_amdgcn_ds_swizzle(__float_as_int(x), PAT));
}

__device__ __forceinline__ float xor16_add(float x) {
#if __has_builtin(__builtin_amdgcn_permlane16_swap)
    uv2 r = __builtin_amdgcn_permlane16_swap(__float_as_uint(x), __float_as_uint(x),
                                             false, false);
    return __uint_as_float(r.x) + __uint_as_float(r.y);
#else
    return swz_add<0x401F>(x);
#endif
}
__device__ __forceinline__ float xor32_add(float x) {
#if __has_builtin(__builtin_amdgcn_permlane32_swap)
    uv2 r = __builtin_amdgcn_permlane32_swap(__float_as_uint(x), __float_as_uint(x),
                                             false, false);
    return __uint_as_float(r.x) + __uint_as_float(r.y);
#else
    return x + __shfl_xor(x, 32, 64);
#endif
}

__device__ __forceinline__ float reduce1(float a) {
    a = dpp_add<0xB1>(a);
    a = dpp_add<0x4E>(a);
    a = dpp_add<0x141>(a);
    a = swz_add<0x201F>(a);
    a = xor16_add(a);
    a = xor32_add(a);
    return a;
}

__device__ __forceinline__ float incl_scan(float x) {
    x = dpp_add<0x111>(x);
    x = dpp_add<0x112>(x);
    x = dpp_add<0x114>(x);
    x = dpp_add<0x118>(x);
    x = dpp_add<0x142, 0xA, false>(x);
    x = dpp_add<0x143, 0xC, false>(x);
    return x;
}

__device__ __forceinline__ unsigned f2bf(float f) {  // RNE, returns low 16 bits
    unsigned u = __float_as_uint(f);
    return (u + 0x7FFFu + ((u >> 16) & 1u)) >> 16;
}
__device__ __forceinline__ float bf_lo(unsigned u) { return __uint_as_float(u << 16); }
__device__ __forceinline__ float bf_hi(unsigned u) { return __uint_as_float(u & 0xFFFF0000u); }

__device__ __forceinline__ unsigned cvt_pk_bf(float lo, float hi) {
    unsigned r;
    asm("v_cvt_pk_bf16_f32 %0, %1, %2" : "=v"(r) : "v"(lo), "v"(hi));
    return r;
}
__device__ __forceinline__ float bpermf(float v, int srclane) {
    return __int_as_float(__builtin_amdgcn_ds_bpermute(srclane << 2, __float_as_int(v)));
}

// Fused pre-pass, one dispatch:
//   blocks [0,1024)  : v[b][n][d] fp32 -> vh[n][b][d] bf16 (contiguous nt reads, cached writes)
//   block  1024      : bounds/widths/innerPad + zero acc/done
//   block  1025      : full pair sort by node i (hist+scan+scatter in LDS)
__global__ __launch_bounds__(1024) void k_pre(
    const float* __restrict__ v, unsigned* __restrict__ vh32,
    const float* __restrict__ brw, float* __restrict__ bounds,
    float* __restrict__ widths, float* __restrict__ innerPad,
    const int* __restrict__ pairs, int* __restrict__ perm,
    double* __restrict__ acc, int* __restrict__ done) {
    __shared__ int scnt[2048];
    __shared__ int waveTot[16];
    __shared__ int waveOff[16];
    const int bid = blockIdx.x;
    const int tid = threadIdx.x;

    if (bid < 1024) {  // ---- convert: block covers bin (bid>>4), nodes [(bid&15)*128, +128)
        const int bin = bid >> 4;
        const int node0 = (bid & 15) << 7;
        const fx4* __restrict__ src =
            (const fx4*)(v + (size_t)bin * SS + (size_t)node0 * DD);
        fx4 f0 = __builtin_nontemporal_load(src + tid * 2);
        fx4 f1 = __builtin_nontemporal_load(src + tid * 2 + 1);
        const int nn = tid >> 3;         // node within chunk
        const int d = (tid & 7) * 8;     // dim start
        ux4 o;
        o.x = f2bf(f0.x) | (f2bf(f0.y) << 16);
        o.y = f2bf(f0.z) | (f2bf(f0.w) << 16);
        o.z = f2bf(f1.x) | (f2bf(f1.y) << 16);
        o.w = f2bf(f1.z) | (f2bf(f1.w) << 16);
        *(ux4*)(vh32 + (size_t)(node0 + nn) * 2048 + bin * 32 + d / 2) = o;
        return;
    }

    if (bid == 1024) {  // ---- bounds + zero
        if (tid == 64) *acc = 0.0;
        if (tid == 65) *done = 0;
        if (tid >= 64) return;
        int lane = tid;
        float w = brw[lane];
        float m = w;
#pragma unroll
        for (int s = 32; s >= 1; s >>= 1) m = fmaxf(m, __shfl_xor(m, s, 64));
        float e = expf(w - m);
        float tot = e;
#pragma unroll
        for (int s = 32; s >= 1; s >>= 1) tot += __shfl_xor(tot, s, 64);
        float sm = e / tot;
        float c = sm;
#pragma unroll
        for (int off = 1; off < 64; off <<= 1) {
            float t = __shfl_up(c, off, 64);
            if (lane >= off) c += t;
        }
        float cexcl = __shfl_up(c, 1, 64);
        if (lane == 0) cexcl = 0.f;
        if (lane == 0) bounds[0] = 0.f;
        bounds[lane + 1] = c;
        widths[lane] = c - cexcl;
        innerPad[lane] = (lane == 63) ? 3.4e38f : c;
        return;
    }

    // ---- bid == 1025: single-block sort of pairs by node i
    scnt[tid] = 0;
    scnt[tid + 1024] = 0;
    __syncthreads();
#pragma unroll
    for (int k = 0; k < 16; k++) atomicAdd(&scnt[pairs[k * 1024 + tid]], 1);
    __syncthreads();
    int a = scnt[tid * 2], b2 = scnt[tid * 2 + 1];
    int s = a + b2;
    int lane = tid & 63, wid = tid >> 6;
    int incl = s;
#pragma unroll
    for (int off = 1; off < 64; off <<= 1) {
        int t2 = __shfl_up(incl, off, 64);
        if (lane >= off) incl += t2;
    }
    if (lane == 63) waveTot[wid] = incl;
    __syncthreads();
    if (tid == 0) {
        int r = 0;
        for (int w = 0; w < 16; w++) { waveOff[w] = r; r += waveTot[w]; }
    }
    __syncthreads();
    int run = waveOff[wid] + (incl - s);
    scnt[tid * 2] = run;           // cursors (own slots only -> no hazard)
    scnt[tid * 2 + 1] = run + a;
    __syncthreads();
#pragma unroll
    for (int k = 0; k < 16; k++) {
        int idx = k * 1024 + tid;
        int pos = atomicAdd(&scnt[pairs[idx]], 1);
        perm[pos] = idx;
    }
}

// 8 pairs per wave, 2-deep double-buffered staging (round-14 structure) +
// setprio around MFMA. Plain cached table stores (nt stores regressed: r16).
__global__ __launch_bounds__(256, 2) void k_pairs(
    const float* __restrict__ x0, const uint4* __restrict__ vh4,
    const float* __restrict__ beta, const int* __restrict__ pairs,
    const int* __restrict__ perm, const float* __restrict__ widths,
    float4* __restrict__ table, double* __restrict__ acc_out) {
    __shared__ double bacc[4];
    const int wid = threadIdx.x >> 6;
    const int lane = threadIdx.x & 63;
    const int bid = blockIdx.x;
    const int vb = ((bid & 7) << 6) | (bid >> 3);  // XCD swizzle over 512 blocks
    const int pbase = (vb * 4 + wid) * 8;

    int pk[8], ik[8], jk[8];
    float bs[8];
#pragma unroll
    for (int k = 0; k < 8; k++) pk[k] = perm[pbase + k];
#pragma unroll
    for (int k = 0; k < 8; k++) {
        ik[k] = pairs[pk[k]];
        jk[k] = pairs[PP + pk[k]];
    }
#pragma unroll
    for (int k = 0; k < 8; k++) bs[k] = beta[ik[k]] + beta[jk[k]];

    float wv[4][4];
#pragma unroll
    for (int tm = 0; tm < 4; tm++)
#pragma unroll
        for (int r = 0; r < 4; r++)
            wv[tm][r] = widths[16 * tm + (lane >> 4) * 4 + r];
    const float wl = widths[lane];
    const int laneterm = (lane & 15) * 8 + (lane >> 4);
    const int nl = lane & 15;
    const int mb = (lane >> 4) * 4;

    uint4 ra0[8], rb0[8], ra1[8], rb1[8];
    float xi0, xj0, xi1, xj1;

#define ISSUE(RA, RB, XI, XJ, k_)                                            \
    {                                                                        \
        const uint4* Vi = vh4 + (size_t)ik[k_] * 512 + laneterm;             \
        const uint4* Vj = vh4 + (size_t)jk[k_] * 512 + laneterm;             \
        _Pragma("unroll") for (int t = 0; t < 4; t++) {                      \
            RA[t * 2 + 0] = Vi[t * 128];                                     \
            RA[t * 2 + 1] = Vi[t * 128 + 4];                                 \
            RB[t * 2 + 0] = Vj[t * 128];                                     \
            RB[t * 2 + 1] = Vj[t * 128 + 4];                                 \
        }                                                                    \
        XI = x0[ik[k_] * DD + lane];                                         \
        XJ = x0[jk[k_] * DD + lane];                                         \
    }

    double accd = 0.0;

#define STEP(RA, RB, XI, XJ, k_, NEXTISSUE)                                                    \
    {                                                                                          \
        const float bsum = bs[k_];                                                             \
        float dx0 = XI - XJ;                                                                   \
        float n2_0 = reduce1(dx0 * dx0);                                                       \
        float rr0 = __builtin_amdgcn_sqrtf(n2_0);                                              \
        float numer0 = rr0 * __expf(bsum - rr0);                                               \
        bf16x8 F[8];                                                                           \
        _Pragma("unroll") for (int f = 0; f < 8; f++) {                                        \
            uint4 q;                                                                           \
            q.x = cvt_pk_bf(bf_lo(RA[f].x) - bf_lo(RB[f].x), bf_hi(RA[f].x) - bf_hi(RB[f].x)); \
            q.y = cvt_pk_bf(bf_lo(RA[f].y) - bf_lo(RB[f].y), bf_hi(RA[f].y) - bf_hi(RB[f].y)); \
            q.z = cvt_pk_bf(bf_lo(RA[f].z) - bf_lo(RB[f].z), bf_hi(RA[f].z) - bf_hi(RB[f].z)); \
            q.w = cvt_pk_bf(bf_lo(RA[f].w) - bf_lo(RB[f].w), bf_hi(RA[f].w) - bf_hi(RB[f].w)); \
            union { uint4 u; bf16x8 s; } cv;                                                   \
            cv.u = q;                                                                          \
            F[f] = cv.s;                                                                       \
        }                                                                                      \
        NEXTISSUE                                                                              \
        bf16x8 AX[2];                                                                          \
        _Pragma("unroll") for (int kb = 0; kb < 2; kb++) {                                     \
            unsigned u[4];                                                                     \
            _Pragma("unroll") for (int c2 = 0; c2 < 4; c2++) {                                 \
                int k0 = kb * 32 + ((lane >> 4) << 3) + c2 * 2;                                \
                u[c2] = cvt_pk_bf(bpermf(dx0, k0), bpermf(dx0, k0 + 1));                       \
            }                                                                                  \
            uint4 q;                                                                           \
            bool z = (lane & 15) != 0;                                                         \
            q.x = z ? 0u : u[0]; q.y = z ? 0u : u[1];                                          \
            q.z = z ? 0u : u[2]; q.w = z ? 0u : u[3];                                          \
            union { uint4 uu; bf16x8 s; } cv;                                                  \
            cv.uu = q;                                                                         \
            AX[kb] = cv.s;                                                                     \
        }                                                                                      \
        __builtin_amdgcn_s_setprio(1);                                                         \
        f32x4v g00 = {0.f, 0.f, 0.f, 0.f}, g01 = g00, g02 = g00, g03 = g00;                    \
        f32x4v g11 = g00, g12 = g00, g13 = g00, g22 = g00, g23 = g00, g33 = g00;               \
        GMM(g00, 0, 0) GMM(g01, 0, 1) GMM(g02, 0, 2) GMM(g03, 0, 3)                            \
        GMM(g11, 1, 1) GMM(g12, 1, 2) GMM(g13, 1, 3)                                           \
        GMM(g22, 2, 2) GMM(g23, 2, 3) GMM(g33, 3, 3)                                           \
        float c00, c01, c02, c03;                                                              \
        {                                                                                      \
            f32x4v ca = {0.f, 0.f, 0.f, 0.f};                                                  \
            CMM(0) c00 = ca[0]; ca = {0.f, 0.f, 0.f, 0.f};                                     \
            CMM(1) c01 = ca[0]; ca = {0.f, 0.f, 0.f, 0.f};                                     \
            CMM(2) c02 = ca[0]; ca = {0.f, 0.f, 0.f, 0.f};                                     \
            CMM(3) c03 = ca[0];                                                                \
        }                                                                                      \
        __builtin_amdgcn_s_setprio(0);                                                         \
        float c0v;                                                                             \
        {                                                                                      \
            float b0 = bpermf(c00, lane & 15);                                                 \
            float b1 = bpermf(c01, lane & 15);                                                 \
            float b2 = bpermf(c02, lane & 15);                                                 \
            float b3 = bpermf(c03, lane & 15);                                                 \
            int g = lane >> 4;                                                                 \
            c0v = (g == 0) ? b0 : (g == 1) ? b1 : (g == 2) ? b2 : b3;                          \
        }                                                                                      \
        float Sv = 0.f, qv = 0.f;                                                              \
        { float sp = 0.f, qp = 0.f;                                 DIAG(g00, 0) FINTN(0) }    \
        { float sp = OFFT(g01, 0), qp = 0.f;                        DIAG(g11, 1) FINTN(1) }    \
        { float sp = OFFT(g02, 0) + OFFT(g12, 1), qp = 0.f;         DIAG(g22, 2) FINTN(2) }    \
        { float sp = OFFT(g03, 0) + OFFT(g13, 1) + OFFT(g23, 2), qp = 0.f;                     \
                                                                    DIAG(g33, 3) FINTN(3) }    \
        float d0r = c0v + Sv;                                                                  \
        float qqr = qv;                                                                        \
        float tt = wl * fmaf(wl, qqr, 2.f * d0r);                                              \
        float incl = incl_scan(tt);                                                            \
        float n2L = fmaxf(n2_0 + (incl - tt), 0.f);                                            \
        float n2R = fmaxf(n2_0 + incl, 0.f);                                                   \
        float rrR = __builtin_amdgcn_sqrtf(n2R);                                               \
        float numerR = rrR * __expf(bsum - rrR);                                               \
        float numerL = __int_as_float(                                                         \
            __builtin_amdgcn_update_dpp(0, __float_as_int(numerR), 0x138, 0xF, 0xF, true));    \
        numerL = (lane == 0) ? numer0 : numerL;                                                \
        float pd = fmaf(wl, qqr, d0r);                                                         \
        float term = numerR * __builtin_amdgcn_rcpf(pd + EPSF)                                 \
                   - numerL * __builtin_amdgcn_rcpf(d0r + EPSF);                               \
        float acc = reduce1(term);                                                             \
        table[(size_t)pk[k_] * BB + lane] = make_float4(n2L, d0r, qqr, bsum);                  \
        accd += (double)acc;                                                                   \
    }

#define GMM(acc, ta, tb)                                                                       \
    acc = __builtin_amdgcn_mfma_f32_16x16x32_bf16(F[(ta)*2 + 0], F[(tb)*2 + 0], acc, 0, 0, 0); \
    acc = __builtin_amdgcn_mfma_f32_16x16x32_bf16(F[(ta)*2 + 1], F[(tb)*2 + 1], acc, 0, 0, 0);
#define CMM(tb)                                                                       \
    ca = __builtin_amdgcn_mfma_f32_16x16x32_bf16(AX[0], F[(tb)*2 + 0], ca, 0, 0, 0); \
    ca = __builtin_amdgcn_mfma_f32_16x16x32_bf16(AX[1], F[(tb)*2 + 1], ca, 0, 0, 0);
#define OFFT(gt, t_) (wv[t_][0] * gt[0] + wv[t_][1] * gt[1] + wv[t_][2] * gt[2] + wv[t_][3] * gt[3])
#define DIAG(d, t_)                                       \
    sp += (mb + 0 < nl) ? wv[t_][0] * d[0] : 0.f;         \
    sp += (mb + 1 < nl) ? wv[t_][1] * d[1] : 0.f;         \
    sp += (mb + 2 < nl) ? wv[t_][2] * d[2] : 0.f;         \
    sp += (mb + 3 < nl) ? wv[t_][3] * d[3] : 0.f;         \
    qp += (mb + 0 == nl) ? d[0] : 0.f;                    \
    qp += (mb + 1 == nl) ? d[1] : 0.f;                    \
    qp += (mb + 2 == nl) ? d[2] : 0.f;                    \
    qp += (mb + 3 == nl) ? d[3] : 0.f;
#define FINTN(t_)                                         \
    sp = xor16_add(sp); sp = xor32_add(sp);               \
    qp = xor16_add(qp); qp = xor32_add(qp);               \
    if ((lane >> 4) == t_) { Sv = sp; qv = qp; }

    ISSUE(ra0, rb0, xi0, xj0, 0)
    ISSUE(ra1, rb1, xi1, xj1, 1)

    STEP(ra0, rb0, xi0, xj0, 0, ISSUE(ra0, rb0, xi0, xj0, 2))
    STEP(ra1, rb1, xi1, xj1, 1, ISSUE(ra1, rb1, xi1, xj1, 3))
    STEP(ra0, rb0, xi0, xj0, 2, ISSUE(ra0, rb0, xi0, xj0, 4))
    STEP(ra1, rb1, xi1, xj1, 3, ISSUE(ra1, rb1, xi1, xj1, 5))
    STEP(ra0, rb0, xi0, xj0, 4, ISSUE(ra0, rb0, xi0, xj0, 6))
    STEP(ra1, rb1, xi1, xj1, 5, ISSUE(ra1, rb1, xi1, xj1, 7))
    STEP(ra0, rb0, xi0, xj0, 6, )
    STEP(ra1, rb1, xi1, xj1, 7, )

#undef ISSUE
#undef STEP
#undef GMM
#undef CMM
#undef OFFT
#undef DIAG
#undef FINTN

    if (lane == 0) bacc[wid] = accd;
    __syncthreads();
    if (threadIdx.x == 0)
        atomicAdd(acc_out, bacc[0] + bacc[1] + bacc[2] + bacc[3]);
}

// events + fused finalize (last block writes the output)
__global__ __launch_bounds__(256) void k_events(
    const float* __restrict__ times, const int* __restrict__ epid,
    const float* __restrict__ bounds, const float* __restrict__ innerPad,
    const float4* __restrict__ table, double* __restrict__ acc_out,
    int* __restrict__ done, float* __restrict__ out) {
    __shared__ float si[64];
    __shared__ float sb[BB + 1];
    __shared__ double wacc[4];
    int tid = threadIdx.x;
    if (tid < 64) si[tid] = innerPad[tid];
    if (tid <= BB) sb[tid] = bounds[tid];
    __syncthreads();
    int g = (blockIdx.x * 256 + tid) * 2;
    float2 tm2 = *(const float2*)(times + g);
    int2 pd2 = *(const int2*)(epid + g);
    float tms[2] = {tm2.x, tm2.y};
    int pids[2] = {pd2.x, pd2.y};
    int cc[2];
    float rem[2];
#pragma unroll
    for (int k = 0; k < 2; k++) {
        int c = 0;
        float tm = tms[k];
#pragma unroll
        for (int s = 32; s >= 1; s >>= 1)
            if (si[c + s - 1] <= tm) c += s;
        cc[k] = c;
        rem[k] = tm - sb[c];
    }
    float4 e0 = table[(size_t)pids[0] * BB + cc[0]];
    float4 e1 = table[(size_t)pids[1] * BB + cc[1]];
    float eacc;
    {
        float d2 = fmaxf(fmaf(rem[0], fmaf(rem[0], e0.z, 2.f * e0.y), e0.x), 0.f);
        eacc = e0.w - __builtin_amdgcn_sqrtf(d2);
        d2 = fmaxf(fmaf(rem[1], fmaf(rem[1], e1.z, 2.f * e1.y), e1.x), 0.f);
        eacc += e1.w - __builtin_amdgcn_sqrtf(d2);
    }
    float val = reduce1(eacc);
    if ((tid & 63) == 0) wacc[tid >> 6] = (double)val;
    __syncthreads();
    if (tid == 0) {
        atomicAdd(acc_out, -(wacc[0] + wacc[1] + wacc[2] + wacc[3]));
        __threadfence();
        int c = atomicAdd(done, 1);
        if (c == (int)gridDim.x - 1) {
            double a = atomicAdd(acc_out, 0.0);  // atomic read: all adds visible
            out[0] = (float)a;
        }
    }
}

extern "C" void kernel_launch(void* const* d_in, const int* in_sizes, int n_in,
                              void* d_out, int out_size, void* d_ws, size_t ws_size,
                              hipStream_t stream) {
    const float* x0     = (const float*)d_in[0];
    const float* v      = (const float*)d_in[1];
    const float* beta   = (const float*)d_in[2];
    const float* brw    = (const float*)d_in[3];
    const float* etimes = (const float*)d_in[4];
    const int*   pairs  = (const int*)d_in[5];
    const int*   epid   = (const int*)d_in[6];

    char* ws = (char*)d_ws;
    double* acc     = (double*)ws;
    int* done       = (int*)(ws + 1024);
    int* perm       = (int*)(ws + 17408);
    float* bounds   = (float*)(ws + 82944);
    float* widths   = (float*)(ws + 83456);
    float* innerPad = (float*)(ws + 83968);
    float4* table   = (float4*)(ws + 84480);
    unsigned* vh32  = (unsigned*)(ws + 84480 + (size_t)PP * BB * 16);

    hipLaunchKernelGGL(k_pre, dim3(1026), dim3(1024), 0, stream, v, vh32, brw,
                       bounds, widths, innerPad, pairs, perm, acc, done);
    hipLaunchKernelGGL(k_pairs, dim3(PP / 32), dim3(256), 0, stream, x0, (const uint4*)vh32,
                       beta, pairs, perm, widths, table, acc);
    hipLaunchKernelGGL(k_events, dim3(TT / 512), dim3(256), 0, stream, etimes, epid,
                       bounds, innerPad, table, acc, done, (float*)d_out);
}

// Round 18
// 74.702 us; speedup vs baseline: 1.2539x; 1.2215x over previous
//
#include <hip/hip_runtime.h>

#define NN 2048
#define DD 64
#define BB 64
#define PP 16384
#define TT 262144
#define EPSF 1e-6f
#define SS ((size_t)NN * DD)  // floats between consecutive bins of v (bin-major)

// ---------------- ws layout (bytes) ----------------
// 0        : double acc
// 1024     : int done
// 17408    : int perm[PP]      (pair ids sorted by node i)
// 82944    : float bounds[65]
// 83456    : float widths[64]
// 83968    : float innerPad[64]
// 84480    : float4 table[PP*BB]  (n2_left, d0, qq, bsum) = 16.78 MB
// 16861696 : ushort vh[NN*BB*DD]  (bf16 node-major v)      = 16.78 MB

typedef unsigned uv2 __attribute__((ext_vector_type(2)));
typedef float fx4 __attribute__((ext_vector_type(4)));
typedef unsigned ux4 __attribute__((ext_vector_type(4)));
using bf16x8 = __attribute__((ext_vector_type(8))) short;
using f32x4v = __attribute__((ext_vector_type(4))) float;

template <int CTRL, int RM = 0xF, bool BC = true>
__device__ __forceinline__ float dpp_add(float x) {
    int y = __builtin_amdgcn_update_dpp(0, __float_as_int(x), CTRL, RM, 0xF, BC);
    return x + __int_as_float(y);
}

template <int PAT>
__device__ __forceinline__ float swz_add(float x) {
    return x + __int_as_float(__builtin_amdgcn_ds_swizzle(__float_as_int(x), PAT));
}

__device__ __forceinline__ float xor16_add(float x) {
#if __has_builtin(__builtin_amdgcn_permlane16_swap)
    uv2 r = __builtin_amdgcn_permlane16_swap(__float_as_uint(x), __float_as_uint(x),
                                             false, false);
    return __uint_as_float(r.x) + __uint_as_float(r.y);
#else
    return swz_add<0x401F>(x);
#endif
}
__device__ __forceinline__ float xor32_add(float x) {
#if __has_builtin(__builtin_amdgcn_permlane32_swap)
    uv2 r = __builtin_amdgcn_permlane32_swap(__float_as_uint(x), __float_as_uint(x),
                                             false, false);
    return __uint_as_float(r.x) + __uint_as_float(r.y);
#else
    return x + __shfl_xor(x, 32, 64);
#endif
}

__device__ __forceinline__ float reduce1(float a) {
    a = dpp_add<0xB1>(a);
    a = dpp_add<0x4E>(a);
    a = dpp_add<0x141>(a);
    a = swz_add<0x201F>(a);
    a = xor16_add(a);
    a = xor32_add(a);
    return a;
}

__device__ __forceinline__ float incl_scan(float x) {
    x = dpp_add<0x111>(x);
    x = dpp_add<0x112>(x);
    x = dpp_add<0x114>(x);
    x = dpp_add<0x118>(x);
    x = dpp_add<0x142, 0xA, false>(x);
    x = dpp_add<0x143, 0xC, false>(x);
    return x;
}

__device__ __forceinline__ unsigned f2bf(float f) {  // RNE, returns low 16 bits
    unsigned u = __float_as_uint(f);
    return (u + 0x7FFFu + ((u >> 16) & 1u)) >> 16;
}
__device__ __forceinline__ float bf_lo(unsigned u) { return __uint_as_float(u << 16); }
__device__ __forceinline__ float bf_hi(unsigned u) { return __uint_as_float(u & 0xFFFF0000u); }

__device__ __forceinline__ unsigned cvt_pk_bf(float lo, float hi) {
    unsigned r;
    asm("v_cvt_pk_bf16_f32 %0, %1, %2" : "=v"(r) : "v"(lo), "v"(hi));
    return r;
}
__device__ __forceinline__ float bpermf(float v, int srclane) {
    return __int_as_float(__builtin_amdgcn_ds_bpermute(srclane << 2, __float_as_int(v)));
}

// Fused pre-pass, one dispatch:
//   blocks [0,1024)  : v[b][n][d] fp32 -> vh[n][b][d] bf16 (contiguous nt reads, cached writes)
//   block  1024      : bounds/widths/innerPad + zero acc/done
//   block  1025      : full pair sort by node i (hist+scan+scatter in LDS)
__global__ __launch_bounds__(1024) void k_pre(
    const float* __restrict__ v, unsigned* __restrict__ vh32,
    const float* __restrict__ brw, float* __restrict__ bounds,
    float* __restrict__ widths, float* __restrict__ innerPad,
    const int* __restrict__ pairs, int* __restrict__ perm,
    double* __restrict__ acc, int* __restrict__ done) {
    __shared__ int scnt[2048];
    __shared__ int waveTot[16];
    __shared__ int waveOff[16];
    const int bid = blockIdx.x;
    const int tid = threadIdx.x;

    if (bid < 1024) {  // ---- convert: block covers bin (bid>>4), nodes [(bid&15)*128, +128)
        const int bin = bid >> 4;
        const int node0 = (bid & 15) << 7;
        const fx4* __restrict__ src =
            (const fx4*)(v + (size_t)bin * SS + (size_t)node0 * DD);
        fx4 f0 = __builtin_nontemporal_load(src + tid * 2);
        fx4 f1 = __builtin_nontemporal_load(src + tid * 2 + 1);
        const int nn = tid >> 3;         // node within chunk
        const int d = (tid & 7) * 8;     // dim start
        ux4 o;
        o.x = f2bf(f0.x) | (f2bf(f0.y) << 16);
        o.y = f2bf(f0.z) | (f2bf(f0.w) << 16);
        o.z = f2bf(f1.x) | (f2bf(f1.y) << 16);
        o.w = f2bf(f1.z) | (f2bf(f1.w) << 16);
        *(ux4*)(vh32 + (size_t)(node0 + nn) * 2048 + bin * 32 + d / 2) = o;
        return;
    }

    if (bid == 1024) {  // ---- bounds + zero
        if (tid == 64) *acc = 0.0;
        if (tid == 65) *done = 0;
        if (tid >= 64) return;
        int lane = tid;
        float w = brw[lane];
        float m = w;
#pragma unroll
        for (int s = 32; s >= 1; s >>= 1) m = fmaxf(m, __shfl_xor(m, s, 64));
        float e = expf(w - m);
        float tot = e;
#pragma unroll
        for (int s = 32; s >= 1; s >>= 1) tot += __shfl_xor(tot, s, 64);
        float sm = e / tot;
        float c = sm;
#pragma unroll
        for (int off = 1; off < 64; off <<= 1) {
            float t = __shfl_up(c, off, 64);
            if (lane >= off) c += t;
        }
        float cexcl = __shfl_up(c, 1, 64);
        if (lane == 0) cexcl = 0.f;
        if (lane == 0) bounds[0] = 0.f;
        bounds[lane + 1] = c;
        widths[lane] = c - cexcl;
        innerPad[lane] = (lane == 63) ? 3.4e38f : c;
        return;
    }

    // ---- bid == 1025: single-block sort of pairs by node i
    scnt[tid] = 0;
    scnt[tid + 1024] = 0;
    __syncthreads();
#pragma unroll
    for (int k = 0; k < 16; k++) atomicAdd(&scnt[pairs[k * 1024 + tid]], 1);
    __syncthreads();
    int a = scnt[tid * 2], b2 = scnt[tid * 2 + 1];
    int s = a + b2;
    int lane = tid & 63, wid = tid >> 6;
    int incl = s;
#pragma unroll
    for (int off = 1; off < 64; off <<= 1) {
        int t2 = __shfl_up(incl, off, 64);
        if (lane >= off) incl += t2;
    }
    if (lane == 63) waveTot[wid] = incl;
    __syncthreads();
    if (tid == 0) {
        int r = 0;
        for (int w = 0; w < 16; w++) { waveOff[w] = r; r += waveTot[w]; }
    }
    __syncthreads();
    int run = waveOff[wid] + (incl - s);
    scnt[tid * 2] = run;           // cursors (own slots only -> no hazard)
    scnt[tid * 2 + 1] = run + a;
    __syncthreads();
#pragma unroll
    for (int k = 0; k < 16; k++) {
        int idx = k * 1024 + tid;
        int pos = atomicAdd(&scnt[pairs[idx]], 1);
        perm[pos] = idx;
    }
}

// 8 pairs per wave, single rotating staging buffer (no spill) + i-side reuse:
// RA/xi reloaded only when node i changes (wave-uniform scalar branch).
// J-load for pair k+1 issues after pair k's convert, covered by MFMA+phase3.
__global__ __launch_bounds__(256, 2) void k_pairs(
    const float* __restrict__ x0, const uint4* __restrict__ vh4,
    const float* __restrict__ beta, const int* __restrict__ pairs,
    const int* __restrict__ perm, const float* __restrict__ widths,
    float4* __restrict__ table, double* __restrict__ acc_out) {
    __shared__ double bacc[4];
    const int wid = threadIdx.x >> 6;
    const int lane = threadIdx.x & 63;
    const int bid = blockIdx.x;
    const int vb = ((bid & 7) << 6) | (bid >> 3);  // XCD swizzle over 512 blocks
    const int pbase = (vb * 4 + wid) * 8;

    int pk[8], ik[8], jk[8];
    float bs[8];
#pragma unroll
    for (int k = 0; k < 8; k++) pk[k] = perm[pbase + k];
#pragma unroll
    for (int k = 0; k < 8; k++) {
        ik[k] = pairs[pk[k]];
        jk[k] = pairs[PP + pk[k]];
    }
#pragma unroll
    for (int k = 0; k < 8; k++) bs[k] = beta[ik[k]] + beta[jk[k]];

    float wv[4][4];
#pragma unroll
    for (int tm = 0; tm < 4; tm++)
#pragma unroll
        for (int r = 0; r < 4; r++)
            wv[tm][r] = widths[16 * tm + (lane >> 4) * 4 + r];
    const float wl = widths[lane];
    const int laneterm = (lane & 15) * 8 + (lane >> 4);
    const int nl = lane & 15;
    const int mb = (lane >> 4) * 4;

    uint4 RA[8], RB[8];  // single staging pair: i-side persistent, j-side rotating
    float xi, xj;
    {
        const uint4* Vi = vh4 + (size_t)ik[0] * 512 + laneterm;
#pragma unroll
        for (int t = 0; t < 4; t++) {
            RA[t * 2 + 0] = Vi[t * 128];
            RA[t * 2 + 1] = Vi[t * 128 + 4];
        }
        xi = x0[ik[0] * DD + lane];
    }
    {
        const uint4* Vj = vh4 + (size_t)jk[0] * 512 + laneterm;
#pragma unroll
        for (int t = 0; t < 4; t++) {
            RB[t * 2 + 0] = Vj[t * 128];
            RB[t * 2 + 1] = Vj[t * 128 + 4];
        }
        xj = x0[jk[0] * DD + lane];
    }

    double accd = 0.0;

#define OFFT(gt, t_) (wv[t_][0] * gt[0] + wv[t_][1] * gt[1] + wv[t_][2] * gt[2] + wv[t_][3] * gt[3])
#define DIAG(d, t_)                                       \
    sp += (mb + 0 < nl) ? wv[t_][0] * d[0] : 0.f;         \
    sp += (mb + 1 < nl) ? wv[t_][1] * d[1] : 0.f;         \
    sp += (mb + 2 < nl) ? wv[t_][2] * d[2] : 0.f;         \
    sp += (mb + 3 < nl) ? wv[t_][3] * d[3] : 0.f;         \
    qp += (mb + 0 == nl) ? d[0] : 0.f;                    \
    qp += (mb + 1 == nl) ? d[1] : 0.f;                    \
    qp += (mb + 2 == nl) ? d[2] : 0.f;                    \
    qp += (mb + 3 == nl) ? d[3] : 0.f;
#define FINTN(t_)                                         \
    sp = xor16_add(sp); sp = xor32_add(sp);               \
    qp = xor16_add(qp); qp = xor32_add(qp);               \
    if ((lane >> 4) == t_) { Sv = sp; qv = qp; }
#define GMM(acc, ta, tb)                                                                       \
    acc = __builtin_amdgcn_mfma_f32_16x16x32_bf16(F[(ta)*2 + 0], F[(tb)*2 + 0], acc, 0, 0, 0); \
    acc = __builtin_amdgcn_mfma_f32_16x16x32_bf16(F[(ta)*2 + 1], F[(tb)*2 + 1], acc, 0, 0, 0);
#define CMM(tb)                                                                       \
    ca = __builtin_amdgcn_mfma_f32_16x16x32_bf16(AX[0], F[(tb)*2 + 0], ca, 0, 0, 0); \
    ca = __builtin_amdgcn_mfma_f32_16x16x32_bf16(AX[1], F[(tb)*2 + 1], ca, 0, 0, 0);

#pragma unroll
    for (int k = 0; k < 8; k++) {
        const float bsum = bs[k];
        float dx0 = xi - xj;
        float n2_0 = reduce1(dx0 * dx0);
        float rr0 = __builtin_amdgcn_sqrtf(n2_0);
        float numer0 = rr0 * __expf(bsum - rr0);

        // ---- convert raw staging -> bf16 fragments (RA stays valid for reuse)
        bf16x8 F[8];
#pragma unroll
        for (int f = 0; f < 8; f++) {
            uint4 q;
            q.x = cvt_pk_bf(bf_lo(RA[f].x) - bf_lo(RB[f].x), bf_hi(RA[f].x) - bf_hi(RB[f].x));
            q.y = cvt_pk_bf(bf_lo(RA[f].y) - bf_lo(RB[f].y), bf_hi(RA[f].y) - bf_hi(RB[f].y));
            q.z = cvt_pk_bf(bf_lo(RA[f].z) - bf_lo(RB[f].z), bf_hi(RA[f].z) - bf_hi(RB[f].z));
            q.w = cvt_pk_bf(bf_lo(RA[f].w) - bf_lo(RB[f].w), bf_hi(RA[f].w) - bf_hi(RB[f].w));
            union { uint4 u; bf16x8 s; } cv;
            cv.u = q;
            F[f] = cv.s;
        }

        // ---- prefetch next pair (j always; i only when node changes)
        if (k < 7) {
            if (__builtin_amdgcn_readfirstlane(ik[k + 1]) !=
                __builtin_amdgcn_readfirstlane(ik[k])) {
                const uint4* Vi = vh4 + (size_t)ik[k + 1] * 512 + laneterm;
#pragma unroll
                for (int t = 0; t < 4; t++) {
                    RA[t * 2 + 0] = Vi[t * 128];
                    RA[t * 2 + 1] = Vi[t * 128 + 4];
                }
                xi = x0[ik[k + 1] * DD + lane];
            }
            const uint4* Vj = vh4 + (size_t)jk[k + 1] * 512 + laneterm;
#pragma unroll
            for (int t = 0; t < 4; t++) {
                RB[t * 2 + 0] = Vj[t * 128];
                RB[t * 2 + 1] = Vj[t * 128 + 4];
            }
            xj = x0[jk[k + 1] * DD + lane];
        }

        // ---- A_x fragment: row 0 = dx0 (bf16)
        bf16x8 AX[2];
#pragma unroll
        for (int kb = 0; kb < 2; kb++) {
            unsigned u[4];
#pragma unroll
            for (int c2 = 0; c2 < 4; c2++) {
                int k0 = kb * 32 + ((lane >> 4) << 3) + c2 * 2;
                u[c2] = cvt_pk_bf(bpermf(dx0, k0), bpermf(dx0, k0 + 1));
            }
            uint4 q;
            bool z = (lane & 15) != 0;
            q.x = z ? 0u : u[0]; q.y = z ? 0u : u[1];
            q.z = z ? 0u : u[2]; q.w = z ? 0u : u[3];
            union { uint4 uu; bf16x8 s; } cv;
            cv.uu = q;
            AX[kb] = cv.s;
        }

        // ---- Gram upper-triangle via MFMA
        f32x4v g00 = {0.f, 0.f, 0.f, 0.f}, g01 = g00, g02 = g00, g03 = g00;
        f32x4v g11 = g00, g12 = g00, g13 = g00, g22 = g00, g23 = g00, g33 = g00;
        GMM(g00, 0, 0) GMM(g01, 0, 1) GMM(g02, 0, 2) GMM(g03, 0, 3)
        GMM(g11, 1, 1) GMM(g12, 1, 2) GMM(g13, 1, 3)
        GMM(g22, 2, 2) GMM(g23, 2, 3) GMM(g33, 3, 3)
        float c00, c01, c02, c03;
        {
            f32x4v ca = {0.f, 0.f, 0.f, 0.f};
            CMM(0) c00 = ca[0]; ca = {0.f, 0.f, 0.f, 0.f};
            CMM(1) c01 = ca[0]; ca = {0.f, 0.f, 0.f, 0.f};
            CMM(2) c02 = ca[0]; ca = {0.f, 0.f, 0.f, 0.f};
            CMM(3) c03 = ca[0];
        }

        // ---- c0 broadcast (value on lanes 0-15, col = lane&15)
        float c0v;
        {
            float b0 = bpermf(c00, lane & 15);
            float b1 = bpermf(c01, lane & 15);
            float b2 = bpermf(c02, lane & 15);
            float b3 = bpermf(c03, lane & 15);
            int g = lane >> 4;
            c0v = (g == 0) ? b0 : (g == 1) ? b1 : (g == 2) ? b2 : b3;
        }

        // ---- masked column sums
        float Sv = 0.f, qv = 0.f;
        { float sp = 0.f, qp = 0.f;                                 DIAG(g00, 0) FINTN(0) }
        { float sp = OFFT(g01, 0), qp = 0.f;                        DIAG(g11, 1) FINTN(1) }
        { float sp = OFFT(g02, 0) + OFFT(g12, 1), qp = 0.f;         DIAG(g22, 2) FINTN(2) }
        { float sp = OFFT(g03, 0) + OFFT(g13, 1) + OFFT(g23, 2), qp = 0.f;
                                                                    DIAG(g33, 3) FINTN(3) }
        float d0r = c0v + Sv;
        float qqr = qv;

        // ---- phase 3 (lane = bin)
        float tt = wl * fmaf(wl, qqr, 2.f * d0r);
        float incl = incl_scan(tt);
        float n2L = fmaxf(n2_0 + (incl - tt), 0.f);
        float n2R = fmaxf(n2_0 + incl, 0.f);
        float rrR = __builtin_amdgcn_sqrtf(n2R);
        float numerR = rrR * __expf(bsum - rrR);
        float numerL = __int_as_float(
            __builtin_amdgcn_update_dpp(0, __float_as_int(numerR), 0x138, 0xF, 0xF, true));
        numerL = (lane == 0) ? numer0 : numerL;
        float pd = fmaf(wl, qqr, d0r);
        float term = numerR * __builtin_amdgcn_rcpf(pd + EPSF)
                   - numerL * __builtin_amdgcn_rcpf(d0r + EPSF);
        float acc = reduce1(term);

        table[(size_t)pk[k] * BB + lane] = make_float4(n2L, d0r, qqr, bsum);
        accd += (double)acc;
    }

#undef OFFT
#undef DIAG
#undef FINTN
#undef GMM
#undef CMM

    if (lane == 0) bacc[wid] = accd;
    __syncthreads();
    if (threadIdx.x == 0)
        atomicAdd(acc_out, bacc[0] + bacc[1] + bacc[2] + bacc[3]);
}

// events + fused finalize (last block writes the output)
__global__ __launch_bounds__(256) void k_events(
    const float* __restrict__ times, const int* __restrict__ epid,
    const float* __restrict__ bounds, const float* __restrict__ innerPad,
    const float4* __restrict__ table, double* __restrict__ acc_out,
    int* __restrict__ done, float* __restrict__ out) {
    __shared__ float si[64];
    __shared__ float sb[BB + 1];
    __shared__ double wacc[4];
    int tid = threadIdx.x;
    if (tid < 64) si[tid] = innerPad[tid];
    if (tid <= BB) sb[tid] = bounds[tid];
    __syncthreads();
    int g = (blockIdx.x * 256 + tid) * 2;
    float2 tm2 = *(const float2*)(times + g);
    int2 pd2 = *(const int2*)(epid + g);
    float tms[2] = {tm2.x, tm2.y};
    int pids[2] = {pd2.x, pd2.y};
    int cc[2];
    float rem[2];
#pragma unroll
    for (int k = 0; k < 2; k++) {
        int c = 0;
        float tm = tms[k];
#pragma unroll
        for (int s = 32; s >= 1; s >>= 1)
            if (si[c + s - 1] <= tm) c += s;
        cc[k] = c;
        rem[k] = tm - sb[c];
    }
    float4 e0 = table[(size_t)pids[0] * BB + cc[0]];
    float4 e1 = table[(size_t)pids[1] * BB + cc[1]];
    float eacc;
    {
        float d2 = fmaxf(fmaf(rem[0], fmaf(rem[0], e0.z, 2.f * e0.y), e0.x), 0.f);
        eacc = e0.w - __builtin_amdgcn_sqrtf(d2);
        d2 = fmaxf(fmaf(rem[1], fmaf(rem[1], e1.z, 2.f * e1.y), e1.x), 0.f);
        eacc += e1.w - __builtin_amdgcn_sqrtf(d2);
    }
    float val = reduce1(eacc);
    if ((tid & 63) == 0) wacc[tid >> 6] = (double)val;
    __syncthreads();
    if (tid == 0) {
        atomicAdd(acc_out, -(wacc[0] + wacc[1] + wacc[2] + wacc[3]));
        __threadfence();
        int c = atomicAdd(done, 1);
        if (c == (int)gridDim.x - 1) {
            double a = atomicAdd(acc_out, 0.0);  // atomic read: all adds visible
            out[0] = (float)a;
        }
    }
}

extern "C" void kernel_launch(void* const* d_in, const int* in_sizes, int n_in,
                              void* d_out, int out_size, void* d_ws, size_t ws_size,
                              hipStream_t stream) {
    const float* x0     = (const float*)d_in[0];
    const float* v      = (const float*)d_in[1];
    const float* beta   = (const float*)d_in[2];
    const float* brw    = (const float*)d_in[3];
    const float* etimes = (const float*)d_in[4];
    const int*   pairs  = (const int*)d_in[5];
    const int*   epid   = (const int*)d_in[6];

    char* ws = (char*)d_ws;
    double* acc     = (double*)ws;
    int* done       = (int*)(ws + 1024);
    int* perm       = (int*)(ws + 17408);
    float* bounds   = (float*)(ws + 82944);
    float* widths   = (float*)(ws + 83456);
    float* innerPad = (float*)(ws + 83968);
    float4* table   = (float4*)(ws + 84480);
    unsigned* vh32  = (unsigned*)(ws + 84480 + (size_t)PP * BB * 16);

    hipLaunchKernelGGL(k_pre, dim3(1026), dim3(1024), 0, stream, v, vh32, brw,
                       bounds, widths, innerPad, pairs, perm, acc, done);
    hipLaunchKernelGGL(k_pairs, dim3(PP / 32), dim3(256), 0, stream, x0, (const uint4*)vh32,
                       beta, pairs, perm, widths, table, acc);
    hipLaunchKernelGGL(k_events, dim3(TT / 512), dim3(256), 0, stream, etimes, epid,
                       bounds, innerPad, table, acc, done, (float*)d_out);
}